// Round 2
// baseline (1647.355 us; speedup 1.0000x reference)
//
#include <hip/hip_runtime.h>
#include <math.h>

#define BB    8
#define CC    64
#define NN    256
#define MM    20      // retained modes per axis
#define NKK   40      // retained row-modes: {0..19} U {236..255}
#define NLAY  3
#define FCD   128
#define PLANE (NN*NN)

// ---------------------------------------------------------------------------
// Basis precompute (double precision on device; tiny).
// FlT[y*MM+l]  = g(y)   * cos(pi*l*y/255)                (forward col basis, T = h @ FlT)
// FkT[x*NKK+k] = g(x)   * cos(pi*rk(k)*x/255)            (forward row basis, transposed for LDS b128)
// BkT[k*NN+p]  = gk(k)  * cos(pi*p*rk(k)/255)            (inverse row basis)
// BlT[l*NN+q]  = gl(l)  * cos(pi*q*l/255)                (inverse col basis)
// CwT[lay][i*CC+o] = conv_w[lay][o*CC+i]                 (transposed 1x1-conv weights)
__global__ __launch_bounds__(256) void k_basis(float* __restrict__ FlT, float* __restrict__ FkT,
                                               float* __restrict__ BkT, float* __restrict__ BlT,
                                               float* __restrict__ CwT, const float* __restrict__ conv_w) {
    int t = threadIdx.x;
    const double PI = 3.14159265358979323846;
    for (int j = t; j < NN*MM; j += 256) {
        int y = j / MM, l = j % MM;
        double g = (y == 0 || y == NN-1) ? 1.0 : 2.0;
        FlT[j] = (float)(g * cos(PI * (double)(l*y) / (double)(NN-1)));
    }
    for (int j = t; j < NN*NKK; j += 256) {
        int x = j / NKK, k = j % NKK;
        int rk = (k < MM) ? k : (NN - NKK + k);
        double g = (x == 0 || x == NN-1) ? 1.0 : 2.0;
        FkT[j] = (float)(g * cos(PI * (double)(rk*x) / (double)(NN-1)));
    }
    for (int j = t; j < NKK*NN; j += 256) {
        int k = j / NN, p = j % NN;
        int rk = (k < MM) ? k : (NN - NKK + k);
        double g = (rk == 0 || rk == NN-1) ? 1.0 : 2.0;
        BkT[j] = (float)(g * cos(PI * (double)(rk*p) / (double)(NN-1)));
    }
    for (int j = t; j < MM*NN; j += 256) {
        int l = j / NN, q = j % NN;
        double g = (l == 0) ? 1.0 : 2.0;
        BlT[j] = (float)(g * cos(PI * (double)(q*l) / (double)(NN-1)));
    }
    for (int j = t; j < NLAY*CC*CC; j += 256) {
        int lay = j / (CC*CC), r = j % (CC*CC);
        int i = r / CC, o = r % CC;
        CwT[j] = conv_w[lay*CC*CC + o*CC + i];
    }
}

// ---------------------------------------------------------------------------
// fc0: h[b,c,p,q] = sum_d x[b,p,q,d]*w[d,c] + bias[c].  Block=(b,p), thread=q.
__global__ __launch_bounds__(256) void k_fc0(const float* __restrict__ xin, const float* __restrict__ w,
                                             const float* __restrict__ bias, float* __restrict__ h) {
    __shared__ float xs[NN*3];
    int b = blockIdx.x >> 8, p = blockIdx.x & 255, q = threadIdx.x;
    size_t rowbase = ((size_t)(b*NN + p)*NN) * 3;
    for (int j = q; j < NN*3; j += 256) xs[j] = xin[rowbase + j];
    __syncthreads();
    float v0 = xs[q*3+0], v1 = xs[q*3+1], v2 = xs[q*3+2];
    size_t obase = (size_t)b*CC*PLANE + (size_t)p*NN + q;
    #pragma unroll 8
    for (int c = 0; c < CC; ++c) {
        float hv = bias[c] + v0*w[c] + v1*w[CC+c] + v2*w[2*CC+c];
        h[obase + (size_t)c*PLANE] = hv;
    }
}

// ---------------------------------------------------------------------------
// Forward truncated DCT: per (b,c) plane, G[k,l] = Fk @ h @ FlT.
// Phase 1: P[k,y] = sum_x FkT[x,k]*h[x,y] (thread=y, acc[40] regs, coalesced h reads).
// Phase 2: G[k,l] = sum_y P[k,y]*FlT[y,l].
// Gt layout: [k][b][c][l]  (contiguous per-k chunk for the spectral kernel).
__global__ __launch_bounds__(256) void k_fwd(const float* __restrict__ h, const float* __restrict__ FkT,
                                             const float* __restrict__ FlT, float* __restrict__ Gt) {
    extern __shared__ float lds[];          // NKK*(NN+1) floats = 10280
    int plane = blockIdx.x;                 // b*CC + c
    int t = threadIdx.x;
    const float* hp = h + (size_t)plane * PLANE;
    for (int j = t; j < NKK*NN; j += 256) lds[j] = FkT[j];
    __syncthreads();
    float acc[NKK];
    #pragma unroll
    for (int k = 0; k < NKK; ++k) acc[k] = 0.f;
    #pragma unroll 2
    for (int x = 0; x < NN; ++x) {
        float hv = hp[x*NN + t];
        const float4* f4 = reinterpret_cast<const float4*>(&lds[x*NKK]);
        #pragma unroll
        for (int k4 = 0; k4 < NKK/4; ++k4) {
            float4 wv = f4[k4];
            acc[4*k4+0] += wv.x * hv;
            acc[4*k4+1] += wv.y * hv;
            acc[4*k4+2] += wv.z * hv;
            acc[4*k4+3] += wv.w * hv;
        }
    }
    __syncthreads();                        // done reading FkT from lds
    #pragma unroll
    for (int k = 0; k < NKK; ++k) lds[k*(NN+1) + t] = acc[k];   // P, padded rows
    __syncthreads();
    int b = plane >> 6, c = plane & 63;
    for (int j = t; j < NKK*MM; j += 256) {
        int k = j / MM, l = j % MM;
        float a = 0.f;
        for (int y = 0; y < NN; ++y) a += lds[k*(NN+1) + y] * FlT[y*MM + l];
        Gt[((size_t)(k*BB + b)*CC + c)*MM + l] = a;
    }
}

// ---------------------------------------------------------------------------
// Spectral mode-mix: S[b,o,kb,l] = sum_i G[b,i,kb,l] * w[i,o,kk,l].
// Block = kb (0..39; <20 -> sp_w1, else sp_w2). Thread: o = t&63, wave g = t>>6 handles b={2g,2g+1}.
// S layout: [b*CC+o][k][l].
__global__ __launch_bounds__(256) void k_spec(const float* __restrict__ Gt, const float* __restrict__ w1,
                                              const float* __restrict__ w2, float* __restrict__ S) {
    extern __shared__ float gl[];           // BB*CC*MM = 10240 floats ([b][c][l] order)
    int kb = blockIdx.x;
    int t = threadIdx.x;
    const float* chunk = Gt + (size_t)kb * (BB*CC*MM);
    for (int j = t; j < BB*CC*MM; j += 256) gl[j] = chunk[j];
    __syncthreads();
    int o = t & 63, g = t >> 6;
    int b0 = 2*g, b1 = 2*g + 1;
    const float* wp; int kk;
    if (kb < MM) { wp = w1; kk = kb; } else { wp = w2; kk = kb - MM; }
    float a0[MM], a1[MM];
    #pragma unroll
    for (int l = 0; l < MM; ++l) { a0[l] = 0.f; a1[l] = 0.f; }
    for (int i = 0; i < CC; ++i) {
        const float4* wr4 = reinterpret_cast<const float4*>(wp + ((size_t)(i*CC + o)*MM + kk)*MM);
        const float4* g04 = reinterpret_cast<const float4*>(&gl[(b0*CC + i)*MM]);
        const float4* g14 = reinterpret_cast<const float4*>(&gl[(b1*CC + i)*MM]);
        #pragma unroll
        for (int l4 = 0; l4 < MM/4; ++l4) {
            float4 wv = wr4[l4];
            float4 gv0 = g04[l4];
            float4 gv1 = g14[l4];
            a0[4*l4+0] += wv.x*gv0.x; a0[4*l4+1] += wv.y*gv0.y;
            a0[4*l4+2] += wv.z*gv0.z; a0[4*l4+3] += wv.w*gv0.w;
            a1[4*l4+0] += wv.x*gv1.x; a1[4*l4+1] += wv.y*gv1.y;
            a1[4*l4+2] += wv.z*gv1.z; a1[4*l4+3] += wv.w*gv1.w;
        }
    }
    size_t s0 = ((size_t)(b0*CC + o)*NKK + kb)*MM;
    size_t s1 = ((size_t)(b1*CC + o)*NKK + kb)*MM;
    #pragma unroll
    for (int l = 0; l < MM; ++l) { S[s0 + l] = a0[l]; S[s1 + l] = a1[l]; }
}

// ---------------------------------------------------------------------------
// Inverse stage 1: u[pl,p,l] = sum_k BkT[k,p] * S[pl,k,l].  Block = plane (b*CC+o), thread = p.
__global__ __launch_bounds__(256) void k_inv1(const float* __restrict__ S, const float* __restrict__ BkT,
                                              float* __restrict__ U) {
    __shared__ __align__(16) float sl[NKK*MM];   // 800
    int pl = blockIdx.x, t = threadIdx.x;
    const float* sp = S + (size_t)pl * NKK * MM;
    for (int j = t; j < NKK*MM; j += 256) sl[j] = sp[j];
    __syncthreads();
    float acc[MM];
    #pragma unroll
    for (int l = 0; l < MM; ++l) acc[l] = 0.f;
    for (int k = 0; k < NKK; ++k) {
        float bk = BkT[k*NN + t];
        const float4* s4 = reinterpret_cast<const float4*>(&sl[k*MM]);
        #pragma unroll
        for (int l4 = 0; l4 < MM/4; ++l4) {
            float4 sv = s4[l4];
            acc[4*l4+0] += bk*sv.x; acc[4*l4+1] += bk*sv.y;
            acc[4*l4+2] += bk*sv.z; acc[4*l4+3] += bk*sv.w;
        }
    }
    float* up = U + ((size_t)pl*NN + t)*MM;
    #pragma unroll
    for (int l = 0; l < MM; ++l) up[l] = acc[l];
}

// ---------------------------------------------------------------------------
// Combine IN PLACE: h[b,o,p,q] = (tanh?)( conv(h)[o] + conv_b[o] + sum_l u[b,o,p,l]*BlT[l,q] )
// Block=(b,p), thread=q, acc[64] channels in regs.
// In-place safety: block (b,p) reads ONLY h[b,:,p,:] and writes ONLY h[b,:,p,:];
// within a thread all loads feed acc before any store to the same addresses
// (single non-restrict pointer => compiler preserves load->store order);
// threads within the block touch disjoint q columns; blocks are disjoint rows.
__global__ __launch_bounds__(256) void k_combine(float* h, const float* __restrict__ U,
                                                 const float* __restrict__ BlT, const float* __restrict__ cwt,
                                                 const float* __restrict__ cb, int do_tanh) {
    extern __shared__ float lds[];
    float* cwl = lds;                // CC*CC (layout [i][o])
    float* utl = lds + CC*CC;        // MM*CC (layout [l][o])
    int b = blockIdx.x >> 8, p = blockIdx.x & 255;
    int q = threadIdx.x;
    for (int j = q; j < CC*CC; j += 256) cwl[j] = cwt[j];
    for (int j = q; j < MM*CC; j += 256) {
        int l = j / CC, o = j % CC;
        utl[j] = U[((size_t)(b*CC + o)*NN + p)*MM + l];
    }
    __syncthreads();
    float acc[CC];
    #pragma unroll
    for (int o = 0; o < CC; ++o) acc[o] = cb[o];
    float* hb = h + (size_t)b*CC*PLANE + (size_t)p*NN + q;
    #pragma unroll 2
    for (int i = 0; i < CC; ++i) {
        float hv = hb[(size_t)i*PLANE];
        const float4* cw4 = reinterpret_cast<const float4*>(&cwl[i*CC]);
        #pragma unroll
        for (int o4 = 0; o4 < CC/4; ++o4) {
            float4 wv = cw4[o4];
            acc[4*o4+0] += wv.x*hv; acc[4*o4+1] += wv.y*hv;
            acc[4*o4+2] += wv.z*hv; acc[4*o4+3] += wv.w*hv;
        }
    }
    #pragma unroll 4
    for (int l = 0; l < MM; ++l) {
        float blv = BlT[l*NN + q];
        const float4* u4 = reinterpret_cast<const float4*>(&utl[l*CC]);
        #pragma unroll
        for (int o4 = 0; o4 < CC/4; ++o4) {
            float4 uv = u4[o4];
            acc[4*o4+0] += uv.x*blv; acc[4*o4+1] += uv.y*blv;
            acc[4*o4+2] += uv.z*blv; acc[4*o4+3] += uv.w*blv;
        }
    }
    if (do_tanh) {
        #pragma unroll
        for (int o = 0; o < CC; ++o) hb[(size_t)o*PLANE] = tanhf(acc[o]);
    } else {
        #pragma unroll
        for (int o = 0; o < CC; ++o) hb[(size_t)o*PLANE] = acc[o];
    }
}

// ---------------------------------------------------------------------------
// Final: out[b,p,q] = fc2( tanh( fc1(h[b,:,p,q]) ) ).  Block=(b,p), thread=q, h in regs, fc1_w in LDS.
__global__ __launch_bounds__(256) void k_final(const float* __restrict__ h, const float* __restrict__ w1,
                                               const float* __restrict__ b1, const float* __restrict__ w2,
                                               const float* __restrict__ b2, float* __restrict__ out) {
    extern __shared__ float wl[];            // CC*FCD = 8192 floats
    int b = blockIdx.x >> 8, p = blockIdx.x & 255;
    int q = threadIdx.x;
    for (int j = q; j < CC*FCD; j += 256) wl[j] = w1[j];
    const float* hb = h + (size_t)b*CC*PLANE + (size_t)p*NN + q;
    float hr[CC];
    #pragma unroll
    for (int i = 0; i < CC; ++i) hr[i] = hb[(size_t)i*PLANE];
    __syncthreads();
    float ov = b2[0];
    for (int f4 = 0; f4 < FCD/4; ++f4) {
        float4 a = *reinterpret_cast<const float4*>(&b1[4*f4]);
        #pragma unroll
        for (int i = 0; i < CC; ++i) {
            float4 wv = *reinterpret_cast<const float4*>(&wl[i*FCD + 4*f4]);
            a.x += hr[i]*wv.x; a.y += hr[i]*wv.y;
            a.z += hr[i]*wv.z; a.w += hr[i]*wv.w;
        }
        float4 w2v = *reinterpret_cast<const float4*>(&w2[4*f4]);
        ov += tanhf(a.x)*w2v.x + tanhf(a.y)*w2v.y + tanhf(a.z)*w2v.z + tanhf(a.w)*w2v.w;
    }
    out[(size_t)blockIdx.x*NN + q] = ov;
}

// ---------------------------------------------------------------------------
extern "C" void kernel_launch(void* const* d_in, const int* in_sizes, int n_in,
                              void* d_out, int out_size, void* d_ws, size_t ws_size,
                              hipStream_t stream) {
    const float* x      = (const float*)d_in[0];
    const float* fc0_w  = (const float*)d_in[1];
    const float* fc0_b  = (const float*)d_in[2];
    const float* sp_w1  = (const float*)d_in[3];
    const float* sp_w2  = (const float*)d_in[4];
    const float* conv_w = (const float*)d_in[5];
    const float* conv_b = (const float*)d_in[6];
    const float* fc1_w  = (const float*)d_in[7];
    const float* fc1_b  = (const float*)d_in[8];
    const float* fc2_w  = (const float*)d_in[9];
    const float* fc2_b  = (const float*)d_in[10];

    float* ws = (float*)d_ws;
    const size_t HSZ = (size_t)BB*CC*PLANE;           // 33,554,432 floats (134.2 MB)
    float* hA  = ws;
    float* Gt  = hA + HSZ;                            // NKK*BB*CC*MM = 409,600
    float* S   = Gt + (size_t)NKK*BB*CC*MM;           // BB*CC*NKK*MM = 409,600
    float* U   = S  + (size_t)BB*CC*NKK*MM;           // BB*CC*NN*MM  = 2,621,440
    float* FlT = U  + (size_t)BB*CC*NN*MM;            // NN*MM   =  5,120
    float* FkT = FlT + NN*MM;                         // NN*NKK  = 10,240
    float* BkT = FkT + NN*NKK;                        // NKK*NN  = 10,240
    float* BlT = BkT + NKK*NN;                        // MM*NN   =  5,120
    float* CwT = BlT + MM*NN;                         // NLAY*CC*CC = 12,288
    // total = 37,038,080 floats = 148.2 MB of workspace (was 283 MB w/ double buffer)

    k_basis<<<1, 256, 0, stream>>>(FlT, FkT, BkT, BlT, CwT, conv_w);
    k_fc0<<<BB*NN, 256, 0, stream>>>(x, fc0_w, fc0_b, hA);

    for (int lay = 0; lay < NLAY; ++lay) {
        const float* w1 = sp_w1 + (size_t)lay*CC*CC*MM*MM;
        const float* w2 = sp_w2 + (size_t)lay*CC*CC*MM*MM;
        k_fwd<<<BB*CC, 256, NKK*(NN+1)*sizeof(float), stream>>>(hA, FkT, FlT, Gt);
        k_spec<<<NKK, 256, BB*CC*MM*sizeof(float), stream>>>(Gt, w1, w2, S);
        k_inv1<<<BB*CC, 256, 0, stream>>>(S, BkT, U);
        k_combine<<<BB*NN, 256, (CC*CC + MM*CC)*sizeof(float), stream>>>(
            hA, U, BlT, CwT + lay*CC*CC, conv_b + lay*CC, (lay != NLAY-1) ? 1 : 0);
    }
    k_final<<<BB*NN, 256, CC*FCD*sizeof(float), stream>>>(hA, fc1_w, fc1_b, fc2_w, fc2_b, (float*)d_out);
}

// Round 3
// 1295.117 us; speedup vs baseline: 1.2720x; 1.2720x over previous
//
#include <hip/hip_runtime.h>
#include <math.h>

#define BB    8
#define CC    64
#define NN    256
#define MM    20      // retained modes per axis
#define NKK   40      // retained row-modes: {0..19} U {236..255}
#define NLAY  3
#define FCD   128
#define PLANE (NN*NN)

// ---------------------------------------------------------------------------
// Basis precompute (double precision on device; tiny).
__global__ __launch_bounds__(256) void k_basis(float* __restrict__ FlT, float* __restrict__ FkT,
                                               float* __restrict__ BkT, float* __restrict__ BlT,
                                               float* __restrict__ CwT, const float* __restrict__ conv_w) {
    int t = threadIdx.x;
    const double PI = 3.14159265358979323846;
    for (int j = t; j < NN*MM; j += 256) {
        int y = j / MM, l = j % MM;
        double g = (y == 0 || y == NN-1) ? 1.0 : 2.0;
        FlT[j] = (float)(g * cos(PI * (double)(l*y) / (double)(NN-1)));
    }
    for (int j = t; j < NN*NKK; j += 256) {
        int x = j / NKK, k = j % NKK;
        int rk = (k < MM) ? k : (NN - NKK + k);
        double g = (x == 0 || x == NN-1) ? 1.0 : 2.0;
        FkT[j] = (float)(g * cos(PI * (double)(rk*x) / (double)(NN-1)));
    }
    for (int j = t; j < NKK*NN; j += 256) {
        int k = j / NN, p = j % NN;
        int rk = (k < MM) ? k : (NN - NKK + k);
        double g = (rk == 0 || rk == NN-1) ? 1.0 : 2.0;
        BkT[j] = (float)(g * cos(PI * (double)(rk*p) / (double)(NN-1)));
    }
    for (int j = t; j < MM*NN; j += 256) {
        int l = j / NN, q = j % NN;
        double g = (l == 0) ? 1.0 : 2.0;
        BlT[j] = (float)(g * cos(PI * (double)(q*l) / (double)(NN-1)));
    }
    for (int j = t; j < NLAY*CC*CC; j += 256) {
        int lay = j / (CC*CC), r = j % (CC*CC);
        int i = r / CC, o = r % CC;
        CwT[j] = conv_w[lay*CC*CC + o*CC + i];
    }
}

// ---------------------------------------------------------------------------
// fc0: h[b,c,p,q] = sum_d x[b,p,q,d]*w[d,c] + bias[c].  Block=(b,p), thread=q.
__global__ __launch_bounds__(256) void k_fc0(const float* __restrict__ xin, const float* __restrict__ w,
                                             const float* __restrict__ bias, float* __restrict__ h) {
    __shared__ float xs[NN*3];
    int b = blockIdx.x >> 8, p = blockIdx.x & 255, q = threadIdx.x;
    size_t rowbase = ((size_t)(b*NN + p)*NN) * 3;
    for (int j = q; j < NN*3; j += 256) xs[j] = xin[rowbase + j];
    __syncthreads();
    float v0 = xs[q*3+0], v1 = xs[q*3+1], v2 = xs[q*3+2];
    size_t obase = (size_t)b*CC*PLANE + (size_t)p*NN + q;
    #pragma unroll 8
    for (int c = 0; c < CC; ++c) {
        float hv = bias[c] + v0*w[c] + v1*w[CC+c] + v2*w[2*CC+c];
        h[obase + (size_t)c*PLANE] = hv;
    }
}

// ---------------------------------------------------------------------------
// Forward truncated DCT: per (b,c) plane, G[k,l] = Fk @ h @ FlT.
__global__ __launch_bounds__(256) void k_fwd(const float* __restrict__ h, const float* __restrict__ FkT,
                                             const float* __restrict__ FlT, float* __restrict__ Gt) {
    extern __shared__ float lds[];          // NKK*(NN+1) floats = 10280
    int plane = blockIdx.x;                 // b*CC + c
    int t = threadIdx.x;
    const float* hp = h + (size_t)plane * PLANE;
    for (int j = t; j < NKK*NN; j += 256) lds[j] = FkT[j];
    __syncthreads();
    float acc[NKK];
    #pragma unroll
    for (int k = 0; k < NKK; ++k) acc[k] = 0.f;
    #pragma unroll 2
    for (int x = 0; x < NN; ++x) {
        float hv = hp[x*NN + t];
        const float4* f4 = reinterpret_cast<const float4*>(&lds[x*NKK]);
        #pragma unroll
        for (int k4 = 0; k4 < NKK/4; ++k4) {
            float4 wv = f4[k4];
            acc[4*k4+0] += wv.x * hv;
            acc[4*k4+1] += wv.y * hv;
            acc[4*k4+2] += wv.z * hv;
            acc[4*k4+3] += wv.w * hv;
        }
    }
    __syncthreads();                        // done reading FkT from lds
    #pragma unroll
    for (int k = 0; k < NKK; ++k) lds[k*(NN+1) + t] = acc[k];   // P, padded rows
    __syncthreads();
    int b = plane >> 6, c = plane & 63;
    for (int j = t; j < NKK*MM; j += 256) {
        int k = j / MM, l = j % MM;
        float a = 0.f;
        for (int y = 0; y < NN; ++y) a += lds[k*(NN+1) + y] * FlT[y*MM + l];
        Gt[((size_t)(k*BB + b)*CC + c)*MM + l] = a;
    }
}

// ---------------------------------------------------------------------------
// Spectral mode-mix: S[b,o,kb,l] = sum_i G[b,i,kb,l] * w[i,o,kk,l].
__global__ __launch_bounds__(256) void k_spec(const float* __restrict__ Gt, const float* __restrict__ w1,
                                              const float* __restrict__ w2, float* __restrict__ S) {
    extern __shared__ float gl[];           // BB*CC*MM = 10240 floats ([b][c][l] order)
    int kb = blockIdx.x;
    int t = threadIdx.x;
    const float* chunk = Gt + (size_t)kb * (BB*CC*MM);
    for (int j = t; j < BB*CC*MM; j += 256) gl[j] = chunk[j];
    __syncthreads();
    int o = t & 63, g = t >> 6;
    int b0 = 2*g, b1 = 2*g + 1;
    const float* wp; int kk;
    if (kb < MM) { wp = w1; kk = kb; } else { wp = w2; kk = kb - MM; }
    float a0[MM], a1[MM];
    #pragma unroll
    for (int l = 0; l < MM; ++l) { a0[l] = 0.f; a1[l] = 0.f; }
    for (int i = 0; i < CC; ++i) {
        const float4* wr4 = reinterpret_cast<const float4*>(wp + ((size_t)(i*CC + o)*MM + kk)*MM);
        const float4* g04 = reinterpret_cast<const float4*>(&gl[(b0*CC + i)*MM]);
        const float4* g14 = reinterpret_cast<const float4*>(&gl[(b1*CC + i)*MM]);
        #pragma unroll
        for (int l4 = 0; l4 < MM/4; ++l4) {
            float4 wv = wr4[l4];
            float4 gv0 = g04[l4];
            float4 gv1 = g14[l4];
            a0[4*l4+0] += wv.x*gv0.x; a0[4*l4+1] += wv.y*gv0.y;
            a0[4*l4+2] += wv.z*gv0.z; a0[4*l4+3] += wv.w*gv0.w;
            a1[4*l4+0] += wv.x*gv1.x; a1[4*l4+1] += wv.y*gv1.y;
            a1[4*l4+2] += wv.z*gv1.z; a1[4*l4+3] += wv.w*gv1.w;
        }
    }
    size_t s0 = ((size_t)(b0*CC + o)*NKK + kb)*MM;
    size_t s1 = ((size_t)(b1*CC + o)*NKK + kb)*MM;
    #pragma unroll
    for (int l = 0; l < MM; ++l) { S[s0 + l] = a0[l]; S[s1 + l] = a1[l]; }
}

// ---------------------------------------------------------------------------
// Inverse stage 1: u[pl,p,l] = sum_k BkT[k,p] * S[pl,k,l].  Block = plane (b*CC+o), thread = p.
__global__ __launch_bounds__(256) void k_inv1(const float* __restrict__ S, const float* __restrict__ BkT,
                                              float* __restrict__ U) {
    __shared__ __align__(16) float sl[NKK*MM];   // 800
    int pl = blockIdx.x, t = threadIdx.x;
    const float* sp = S + (size_t)pl * NKK * MM;
    for (int j = t; j < NKK*MM; j += 256) sl[j] = sp[j];
    __syncthreads();
    float acc[MM];
    #pragma unroll
    for (int l = 0; l < MM; ++l) acc[l] = 0.f;
    for (int k = 0; k < NKK; ++k) {
        float bk = BkT[k*NN + t];
        const float4* s4 = reinterpret_cast<const float4*>(&sl[k*MM]);
        #pragma unroll
        for (int l4 = 0; l4 < MM/4; ++l4) {
            float4 sv = s4[l4];
            acc[4*l4+0] += bk*sv.x; acc[4*l4+1] += bk*sv.y;
            acc[4*l4+2] += bk*sv.z; acc[4*l4+3] += bk*sv.w;
        }
    }
    float* up = U + ((size_t)pl*NN + t)*MM;
    #pragma unroll
    for (int l = 0; l < MM; ++l) up[l] = acc[l];
}

// ---------------------------------------------------------------------------
// Combine IN PLACE: h[b,o,p,q] = (tanh?)( conv(h)[o] + conv_b[o] + sum_l u[b,o,p,l]*BlT[l,q] )
__global__ __launch_bounds__(256) void k_combine(float* h, const float* __restrict__ U,
                                                 const float* __restrict__ BlT, const float* __restrict__ cwt,
                                                 const float* __restrict__ cb, int do_tanh) {
    extern __shared__ float lds[];
    float* cwl = lds;                // CC*CC (layout [i][o])
    float* utl = lds + CC*CC;        // MM*CC (layout [l][o])
    int b = blockIdx.x >> 8, p = blockIdx.x & 255;
    int q = threadIdx.x;
    for (int j = q; j < CC*CC; j += 256) cwl[j] = cwt[j];
    for (int j = q; j < MM*CC; j += 256) {
        int l = j / CC, o = j % CC;
        utl[j] = U[((size_t)(b*CC + o)*NN + p)*MM + l];
    }
    __syncthreads();
    float acc[CC];
    #pragma unroll
    for (int o = 0; o < CC; ++o) acc[o] = cb[o];
    float* hb = h + (size_t)b*CC*PLANE + (size_t)p*NN + q;
    #pragma unroll 2
    for (int i = 0; i < CC; ++i) {
        float hv = hb[(size_t)i*PLANE];
        const float4* cw4 = reinterpret_cast<const float4*>(&cwl[i*CC]);
        #pragma unroll
        for (int o4 = 0; o4 < CC/4; ++o4) {
            float4 wv = cw4[o4];
            acc[4*o4+0] += wv.x*hv; acc[4*o4+1] += wv.y*hv;
            acc[4*o4+2] += wv.z*hv; acc[4*o4+3] += wv.w*hv;
        }
    }
    #pragma unroll 4
    for (int l = 0; l < MM; ++l) {
        float blv = BlT[l*NN + q];
        const float4* u4 = reinterpret_cast<const float4*>(&utl[l*CC]);
        #pragma unroll
        for (int o4 = 0; o4 < CC/4; ++o4) {
            float4 uv = u4[o4];
            acc[4*o4+0] += uv.x*blv; acc[4*o4+1] += uv.y*blv;
            acc[4*o4+2] += uv.z*blv; acc[4*o4+3] += uv.w*blv;
        }
    }
    if (do_tanh) {
        #pragma unroll
        for (int o = 0; o < CC; ++o) hb[(size_t)o*PLANE] = tanhf(acc[o]);
    } else {
        #pragma unroll
        for (int o = 0; o < CC; ++o) hb[(size_t)o*PLANE] = acc[o];
    }
}

// ---------------------------------------------------------------------------
// Final: out[b,p,q] = fc2( tanh( fc1(h[b,:,p,q]) ) ).  Block=(b,p), thread=q.
// fc1/fc2 weight indices are wave-uniform -> compiler emits s_load (scalar pipe,
// constant cache) instead of per-lane LDS reads. Inner loop: v_fmac v,s,v.
// No LDS at all. acc chunked FCH=16 to bound VGPR (~hr[64]+a[16]+addr ≈ 96).
__global__ __launch_bounds__(256) void k_final(const float* __restrict__ h, const float* __restrict__ w1,
                                               const float* __restrict__ b1, const float* __restrict__ w2,
                                               const float* __restrict__ b2, float* __restrict__ out) {
    int b = blockIdx.x >> 8, p = blockIdx.x & 255;
    int q = threadIdx.x;
    const float* hb = h + (size_t)b*CC*PLANE + (size_t)p*NN + q;
    float hr[CC];
    #pragma unroll
    for (int i = 0; i < CC; ++i) hr[i] = hb[(size_t)i*PLANE];
    float ov = b2[0];
    const int FCH = 16;
    for (int f0 = 0; f0 < FCD; f0 += FCH) {
        float a[FCH];
        #pragma unroll
        for (int f = 0; f < FCH; ++f) a[f] = b1[f0 + f];
        #pragma unroll 8
        for (int i = 0; i < CC; ++i) {
            float hv = hr[i];
            const float* wr = &w1[i*FCD + f0];      // wave-uniform address -> s_load_dwordx16
            #pragma unroll
            for (int f = 0; f < FCH; ++f) a[f] += hv * wr[f];
        }
        #pragma unroll
        for (int f = 0; f < FCH; ++f) ov += tanhf(a[f]) * w2[f0 + f];
    }
    out[(size_t)blockIdx.x*NN + q] = ov;
}

// ---------------------------------------------------------------------------
extern "C" void kernel_launch(void* const* d_in, const int* in_sizes, int n_in,
                              void* d_out, int out_size, void* d_ws, size_t ws_size,
                              hipStream_t stream) {
    const float* x      = (const float*)d_in[0];
    const float* fc0_w  = (const float*)d_in[1];
    const float* fc0_b  = (const float*)d_in[2];
    const float* sp_w1  = (const float*)d_in[3];
    const float* sp_w2  = (const float*)d_in[4];
    const float* conv_w = (const float*)d_in[5];
    const float* conv_b = (const float*)d_in[6];
    const float* fc1_w  = (const float*)d_in[7];
    const float* fc1_b  = (const float*)d_in[8];
    const float* fc2_w  = (const float*)d_in[9];
    const float* fc2_b  = (const float*)d_in[10];

    float* ws = (float*)d_ws;
    const size_t HSZ = (size_t)BB*CC*PLANE;           // 33,554,432 floats (134.2 MB)
    float* hA  = ws;
    float* Gt  = hA + HSZ;                            // NKK*BB*CC*MM = 409,600
    float* S   = Gt + (size_t)NKK*BB*CC*MM;           // BB*CC*NKK*MM = 409,600
    float* U   = S  + (size_t)BB*CC*NKK*MM;           // BB*CC*NN*MM  = 2,621,440
    float* FlT = U  + (size_t)BB*CC*NN*MM;            // NN*MM   =  5,120
    float* FkT = FlT + NN*MM;                         // NN*NKK  = 10,240
    float* BkT = FkT + NN*NKK;                        // NKK*NN  = 10,240
    float* BlT = BkT + NKK*NN;                        // MM*NN   =  5,120
    float* CwT = BlT + MM*NN;                         // NLAY*CC*CC = 12,288
    // total = 37,038,080 floats = 148.2 MB of workspace

    k_basis<<<1, 256, 0, stream>>>(FlT, FkT, BkT, BlT, CwT, conv_w);
    k_fc0<<<BB*NN, 256, 0, stream>>>(x, fc0_w, fc0_b, hA);

    for (int lay = 0; lay < NLAY; ++lay) {
        const float* w1 = sp_w1 + (size_t)lay*CC*CC*MM*MM;
        const float* w2 = sp_w2 + (size_t)lay*CC*CC*MM*MM;
        k_fwd<<<BB*CC, 256, NKK*(NN+1)*sizeof(float), stream>>>(hA, FkT, FlT, Gt);
        k_spec<<<NKK, 256, BB*CC*MM*sizeof(float), stream>>>(Gt, w1, w2, S);
        k_inv1<<<BB*CC, 256, 0, stream>>>(S, BkT, U);
        k_combine<<<BB*NN, 256, (CC*CC + MM*CC)*sizeof(float), stream>>>(
            hA, U, BlT, CwT + lay*CC*CC, conv_b + lay*CC, (lay != NLAY-1) ? 1 : 0);
    }
    k_final<<<BB*NN, 256, CC*FCD*sizeof(float), stream>>>(hA, fc1_w, fc1_b, fc2_w, fc2_b, (float*)d_out);
}

// Round 4
// 1248.780 us; speedup vs baseline: 1.3192x; 1.0371x over previous
//
#include <hip/hip_runtime.h>
#include <math.h>

#define BB    8
#define CC    64
#define NN    256
#define MM    20      // retained modes per axis
#define NKK   40      // retained row-modes: {0..19} U {236..255}
#define NLAY  3
#define FCD   128
#define PLANE (NN*NN)

// ---------------------------------------------------------------------------
// Basis precompute (double precision on device; tiny).
__global__ __launch_bounds__(256) void k_basis(float* __restrict__ FlT, float* __restrict__ FkT,
                                               float* __restrict__ BkT, float* __restrict__ BlT,
                                               float* __restrict__ CwT, const float* __restrict__ conv_w) {
    int t = threadIdx.x;
    const double PI = 3.14159265358979323846;
    for (int j = t; j < NN*MM; j += 256) {
        int y = j / MM, l = j % MM;
        double g = (y == 0 || y == NN-1) ? 1.0 : 2.0;
        FlT[j] = (float)(g * cos(PI * (double)(l*y) / (double)(NN-1)));
    }
    for (int j = t; j < NN*NKK; j += 256) {
        int x = j / NKK, k = j % NKK;
        int rk = (k < MM) ? k : (NN - NKK + k);
        double g = (x == 0 || x == NN-1) ? 1.0 : 2.0;
        FkT[j] = (float)(g * cos(PI * (double)(rk*x) / (double)(NN-1)));
    }
    for (int j = t; j < NKK*NN; j += 256) {
        int k = j / NN, p = j % NN;
        int rk = (k < MM) ? k : (NN - NKK + k);
        double g = (rk == 0 || rk == NN-1) ? 1.0 : 2.0;
        BkT[j] = (float)(g * cos(PI * (double)(rk*p) / (double)(NN-1)));
    }
    for (int j = t; j < MM*NN; j += 256) {
        int l = j / NN, q = j % NN;
        double g = (l == 0) ? 1.0 : 2.0;
        BlT[j] = (float)(g * cos(PI * (double)(q*l) / (double)(NN-1)));
    }
    for (int j = t; j < NLAY*CC*CC; j += 256) {
        int lay = j / (CC*CC), r = j % (CC*CC);
        int i = r / CC, o = r % CC;
        CwT[j] = conv_w[lay*CC*CC + o*CC + i];
    }
}

// ---------------------------------------------------------------------------
// fc0: h[b,c,p,q] = sum_d x[b,p,q,d]*w[d,c] + bias[c].  Block=(b,p), thread=q.
__global__ __launch_bounds__(256) void k_fc0(const float* __restrict__ xin, const float* __restrict__ w,
                                             const float* __restrict__ bias, float* __restrict__ h) {
    __shared__ float xs[NN*3];
    int b = blockIdx.x >> 8, p = blockIdx.x & 255, q = threadIdx.x;
    size_t rowbase = ((size_t)(b*NN + p)*NN) * 3;
    for (int j = q; j < NN*3; j += 256) xs[j] = xin[rowbase + j];
    __syncthreads();
    float v0 = xs[q*3+0], v1 = xs[q*3+1], v2 = xs[q*3+2];
    size_t obase = (size_t)b*CC*PLANE + (size_t)p*NN + q;
    #pragma unroll 8
    for (int c = 0; c < CC; ++c) {
        float hv = bias[c] + v0*w[c] + v1*w[CC+c] + v2*w[2*CC+c];
        h[obase + (size_t)c*PLANE] = hv;
    }
}

// ---------------------------------------------------------------------------
// Forward truncated DCT: per (b,c) plane, G[k,l] = Fk @ h @ FlT.
// Phase 1: FkT rows read via wave-uniform scalar loads (s_load through constant
// cache) -> inner loop is v_fmac v,s,v; no LDS traffic in phase 1.
// Phase 2: P staged in LDS (padded rows), G written to Gt [k][b][c][l].
__global__ __launch_bounds__(256) void k_fwd(const float* __restrict__ h, const float* __restrict__ FkT,
                                             const float* __restrict__ FlT, float* __restrict__ Gt) {
    __shared__ float P[NKK][NN+1];
    int plane = blockIdx.x;                 // b*CC + c
    int t = threadIdx.x;
    const float* hp = h + (size_t)plane * PLANE;
    float acc[NKK];
    #pragma unroll
    for (int k = 0; k < NKK; ++k) acc[k] = 0.f;
    #pragma unroll 2
    for (int x = 0; x < NN; ++x) {
        float hv = hp[x*NN + t];
        const float* fr = &FkT[x*NKK];      // wave-uniform address -> s_load
        #pragma unroll
        for (int k = 0; k < NKK; ++k) acc[k] += fr[k] * hv;
    }
    #pragma unroll
    for (int k = 0; k < NKK; ++k) P[k][t] = acc[k];
    __syncthreads();
    int b = plane >> 6, c = plane & 63;
    for (int j = t; j < NKK*MM; j += 256) {
        int k = j / MM, l = j % MM;
        float a = 0.f;
        for (int y = 0; y < NN; ++y) a += P[k][y] * FlT[y*MM + l];
        Gt[((size_t)(k*BB + b)*CC + c)*MM + l] = a;
    }
}

// ---------------------------------------------------------------------------
// Spectral mode-mix: S[b,o,kb,l] = sum_i G[b,i,kb,l] * w[i,o,kk,l].
__global__ __launch_bounds__(256) void k_spec(const float* __restrict__ Gt, const float* __restrict__ w1,
                                              const float* __restrict__ w2, float* __restrict__ S) {
    extern __shared__ float gl[];           // BB*CC*MM = 10240 floats ([b][c][l] order)
    int kb = blockIdx.x;
    int t = threadIdx.x;
    const float* chunk = Gt + (size_t)kb * (BB*CC*MM);
    for (int j = t; j < BB*CC*MM; j += 256) gl[j] = chunk[j];
    __syncthreads();
    int o = t & 63, g = t >> 6;
    int b0 = 2*g, b1 = 2*g + 1;
    const float* wp; int kk;
    if (kb < MM) { wp = w1; kk = kb; } else { wp = w2; kk = kb - MM; }
    float a0[MM], a1[MM];
    #pragma unroll
    for (int l = 0; l < MM; ++l) { a0[l] = 0.f; a1[l] = 0.f; }
    for (int i = 0; i < CC; ++i) {
        const float4* wr4 = reinterpret_cast<const float4*>(wp + ((size_t)(i*CC + o)*MM + kk)*MM);
        const float4* g04 = reinterpret_cast<const float4*>(&gl[(b0*CC + i)*MM]);
        const float4* g14 = reinterpret_cast<const float4*>(&gl[(b1*CC + i)*MM]);
        #pragma unroll
        for (int l4 = 0; l4 < MM/4; ++l4) {
            float4 wv = wr4[l4];
            float4 gv0 = g04[l4];
            float4 gv1 = g14[l4];
            a0[4*l4+0] += wv.x*gv0.x; a0[4*l4+1] += wv.y*gv0.y;
            a0[4*l4+2] += wv.z*gv0.z; a0[4*l4+3] += wv.w*gv0.w;
            a1[4*l4+0] += wv.x*gv1.x; a1[4*l4+1] += wv.y*gv1.y;
            a1[4*l4+2] += wv.z*gv1.z; a1[4*l4+3] += wv.w*gv1.w;
        }
    }
    size_t s0 = ((size_t)(b0*CC + o)*NKK + kb)*MM;
    size_t s1 = ((size_t)(b1*CC + o)*NKK + kb)*MM;
    #pragma unroll
    for (int l = 0; l < MM; ++l) { S[s0 + l] = a0[l]; S[s1 + l] = a1[l]; }
}

// ---------------------------------------------------------------------------
// Inverse stage 1: u[pl,p,l] = sum_k BkT[k,p] * S[pl,k,l].  Block = plane (b*CC+o), thread = p.
__global__ __launch_bounds__(256) void k_inv1(const float* __restrict__ S, const float* __restrict__ BkT,
                                              float* __restrict__ U) {
    __shared__ __align__(16) float sl[NKK*MM];   // 800
    int pl = blockIdx.x, t = threadIdx.x;
    const float* sp = S + (size_t)pl * NKK * MM;
    for (int j = t; j < NKK*MM; j += 256) sl[j] = sp[j];
    __syncthreads();
    float acc[MM];
    #pragma unroll
    for (int l = 0; l < MM; ++l) acc[l] = 0.f;
    for (int k = 0; k < NKK; ++k) {
        float bk = BkT[k*NN + t];
        const float4* s4 = reinterpret_cast<const float4*>(&sl[k*MM]);
        #pragma unroll
        for (int l4 = 0; l4 < MM/4; ++l4) {
            float4 sv = s4[l4];
            acc[4*l4+0] += bk*sv.x; acc[4*l4+1] += bk*sv.y;
            acc[4*l4+2] += bk*sv.z; acc[4*l4+3] += bk*sv.w;
        }
    }
    float* up = U + ((size_t)pl*NN + t)*MM;
    #pragma unroll
    for (int l = 0; l < MM; ++l) up[l] = acc[l];
}

// ---------------------------------------------------------------------------
// Combine IN PLACE (layers with tanh): h[b,o,p,q] = tanh( conv(h)[o]+cb[o]+idct )
__global__ __launch_bounds__(256) void k_combine(float* h, const float* __restrict__ U,
                                                 const float* __restrict__ BlT, const float* __restrict__ cwt,
                                                 const float* __restrict__ cb) {
    extern __shared__ float lds[];
    float* cwl = lds;                // CC*CC (layout [i][o])
    float* utl = lds + CC*CC;        // MM*CC (layout [l][o])
    int b = blockIdx.x >> 8, p = blockIdx.x & 255;
    int q = threadIdx.x;
    for (int j = q; j < CC*CC; j += 256) cwl[j] = cwt[j];
    for (int j = q; j < MM*CC; j += 256) {
        int l = j / CC, o = j % CC;
        utl[j] = U[((size_t)(b*CC + o)*NN + p)*MM + l];
    }
    __syncthreads();
    float acc[CC];
    #pragma unroll
    for (int o = 0; o < CC; ++o) acc[o] = cb[o];
    float* hb = h + (size_t)b*CC*PLANE + (size_t)p*NN + q;
    #pragma unroll 4
    for (int i = 0; i < CC; ++i) {
        float hv = hb[(size_t)i*PLANE];
        const float4* cw4 = reinterpret_cast<const float4*>(&cwl[i*CC]);
        #pragma unroll
        for (int o4 = 0; o4 < CC/4; ++o4) {
            float4 wv = cw4[o4];
            acc[4*o4+0] += wv.x*hv; acc[4*o4+1] += wv.y*hv;
            acc[4*o4+2] += wv.z*hv; acc[4*o4+3] += wv.w*hv;
        }
    }
    #pragma unroll 4
    for (int l = 0; l < MM; ++l) {
        float blv = BlT[l*NN + q];
        const float4* u4 = reinterpret_cast<const float4*>(&utl[l*CC]);
        #pragma unroll
        for (int o4 = 0; o4 < CC/4; ++o4) {
            float4 uv = u4[o4];
            acc[4*o4+0] += uv.x*blv; acc[4*o4+1] += uv.y*blv;
            acc[4*o4+2] += uv.z*blv; acc[4*o4+3] += uv.w*blv;
        }
    }
    #pragma unroll
    for (int o = 0; o < CC; ++o) hb[(size_t)o*PLANE] = tanhf(acc[o]);
}

// ---------------------------------------------------------------------------
// Last layer fused: combine (no tanh) -> fc1 -> tanh -> fc2, straight to out.
// Never writes h; k_final's 134 MB re-read and the 134 MB h write are gone.
// fc1/fc2 weights are wave-uniform -> scalar loads.
__global__ __launch_bounds__(256) void k_combine_fc(const float* __restrict__ h, const float* __restrict__ U,
        const float* __restrict__ BlT, const float* __restrict__ cwt, const float* __restrict__ cb,
        const float* __restrict__ w1, const float* __restrict__ b1,
        const float* __restrict__ w2, const float* __restrict__ b2, float* __restrict__ out) {
    extern __shared__ float lds[];
    float* cwl = lds;                // CC*CC (layout [i][o])
    float* utl = lds + CC*CC;        // MM*CC (layout [l][o])
    int b = blockIdx.x >> 8, p = blockIdx.x & 255;
    int q = threadIdx.x;
    for (int j = q; j < CC*CC; j += 256) cwl[j] = cwt[j];
    for (int j = q; j < MM*CC; j += 256) {
        int l = j / CC, o = j % CC;
        utl[j] = U[((size_t)(b*CC + o)*NN + p)*MM + l];
    }
    __syncthreads();
    float acc[CC];
    #pragma unroll
    for (int o = 0; o < CC; ++o) acc[o] = cb[o];
    const float* hb = h + (size_t)b*CC*PLANE + (size_t)p*NN + q;
    #pragma unroll 4
    for (int i = 0; i < CC; ++i) {
        float hv = hb[(size_t)i*PLANE];
        const float4* cw4 = reinterpret_cast<const float4*>(&cwl[i*CC]);
        #pragma unroll
        for (int o4 = 0; o4 < CC/4; ++o4) {
            float4 wv = cw4[o4];
            acc[4*o4+0] += wv.x*hv; acc[4*o4+1] += wv.y*hv;
            acc[4*o4+2] += wv.z*hv; acc[4*o4+3] += wv.w*hv;
        }
    }
    #pragma unroll 4
    for (int l = 0; l < MM; ++l) {
        float blv = BlT[l*NN + q];
        const float4* u4 = reinterpret_cast<const float4*>(&utl[l*CC]);
        #pragma unroll
        for (int o4 = 0; o4 < CC/4; ++o4) {
            float4 uv = u4[o4];
            acc[4*o4+0] += uv.x*blv; acc[4*o4+1] += uv.y*blv;
            acc[4*o4+2] += uv.z*blv; acc[4*o4+3] += uv.w*blv;
        }
    }
    // fc1 -> tanh -> fc2 on the in-register channel vector
    float ov = b2[0];
    const int FCH = 16;
    for (int f0 = 0; f0 < FCD; f0 += FCH) {
        float a[FCH];
        #pragma unroll
        for (int f = 0; f < FCH; ++f) a[f] = b1[f0 + f];
        #pragma unroll 8
        for (int i = 0; i < CC; ++i) {
            float hv = acc[i];
            const float* wr = &w1[i*FCD + f0];   // wave-uniform -> s_load
            #pragma unroll
            for (int f = 0; f < FCH; ++f) a[f] += hv * wr[f];
        }
        #pragma unroll
        for (int f = 0; f < FCH; ++f) ov += tanhf(a[f]) * w2[f0 + f];
    }
    out[(size_t)blockIdx.x*NN + q] = ov;
}

// ---------------------------------------------------------------------------
extern "C" void kernel_launch(void* const* d_in, const int* in_sizes, int n_in,
                              void* d_out, int out_size, void* d_ws, size_t ws_size,
                              hipStream_t stream) {
    const float* x      = (const float*)d_in[0];
    const float* fc0_w  = (const float*)d_in[1];
    const float* fc0_b  = (const float*)d_in[2];
    const float* sp_w1  = (const float*)d_in[3];
    const float* sp_w2  = (const float*)d_in[4];
    const float* conv_w = (const float*)d_in[5];
    const float* conv_b = (const float*)d_in[6];
    const float* fc1_w  = (const float*)d_in[7];
    const float* fc1_b  = (const float*)d_in[8];
    const float* fc2_w  = (const float*)d_in[9];
    const float* fc2_b  = (const float*)d_in[10];

    float* ws = (float*)d_ws;
    const size_t HSZ = (size_t)BB*CC*PLANE;           // 33,554,432 floats (134.2 MB)
    float* hA  = ws;
    float* Gt  = hA + HSZ;                            // NKK*BB*CC*MM = 409,600
    float* S   = Gt + (size_t)NKK*BB*CC*MM;           // BB*CC*NKK*MM = 409,600
    float* U   = S  + (size_t)BB*CC*NKK*MM;           // BB*CC*NN*MM  = 2,621,440
    float* FlT = U  + (size_t)BB*CC*NN*MM;            // NN*MM   =  5,120
    float* FkT = FlT + NN*MM;                         // NN*NKK  = 10,240
    float* BkT = FkT + NN*NKK;                        // NKK*NN  = 10,240
    float* BlT = BkT + NKK*NN;                        // MM*NN   =  5,120
    float* CwT = BlT + MM*NN;                         // NLAY*CC*CC = 12,288
    // total = 37,038,080 floats = 148.2 MB of workspace

    k_basis<<<1, 256, 0, stream>>>(FlT, FkT, BkT, BlT, CwT, conv_w);
    k_fc0<<<BB*NN, 256, 0, stream>>>(x, fc0_w, fc0_b, hA);

    for (int lay = 0; lay < NLAY; ++lay) {
        const float* w1 = sp_w1 + (size_t)lay*CC*CC*MM*MM;
        const float* w2 = sp_w2 + (size_t)lay*CC*CC*MM*MM;
        k_fwd<<<BB*CC, 256, 0, stream>>>(hA, FkT, FlT, Gt);
        k_spec<<<NKK, 256, BB*CC*MM*sizeof(float), stream>>>(Gt, w1, w2, S);
        k_inv1<<<BB*CC, 256, 0, stream>>>(S, BkT, U);
        if (lay != NLAY-1) {
            k_combine<<<BB*NN, 256, (CC*CC + MM*CC)*sizeof(float), stream>>>(
                hA, U, BlT, CwT + lay*CC*CC, conv_b + lay*CC);
        } else {
            k_combine_fc<<<BB*NN, 256, (CC*CC + MM*CC)*sizeof(float), stream>>>(
                hA, U, BlT, CwT + lay*CC*CC, conv_b + lay*CC,
                fc1_w, fc1_b, fc2_w, fc2_b, (float*)d_out);
        }
    }
}

// Round 5
// 1228.544 us; speedup vs baseline: 1.3409x; 1.0165x over previous
//
#include <hip/hip_runtime.h>
#include <math.h>

#define BB    8
#define CC    64
#define NN    256
#define MM    20      // retained modes per axis
#define NKK   40      // retained row-modes: {0..19} U {236..255}
#define NLAY  3
#define FCD   128
#define PLANE (NN*NN)

// Fast tanh: clamp + exp-based. v_exp_f32/v_rcp_f32, ~1e-7 abs error, no branches.
__device__ __forceinline__ float fast_tanh(float x) {
    float xc = fminf(fmaxf(x, -15.f), 15.f);
    float e = __expf(2.f * xc);
    return (e - 1.f) / (e + 1.f);
}

// ---------------------------------------------------------------------------
// Basis precompute (double precision on device; tiny).
__global__ __launch_bounds__(256) void k_basis(float* __restrict__ FlT, float* __restrict__ FkT,
                                               float* __restrict__ BkT, float* __restrict__ BlT,
                                               float* __restrict__ CwT, const float* __restrict__ conv_w) {
    int t = threadIdx.x;
    const double PI = 3.14159265358979323846;
    for (int j = t; j < NN*MM; j += 256) {
        int y = j / MM, l = j % MM;
        double g = (y == 0 || y == NN-1) ? 1.0 : 2.0;
        FlT[j] = (float)(g * cos(PI * (double)(l*y) / (double)(NN-1)));
    }
    for (int j = t; j < NN*NKK; j += 256) {
        int x = j / NKK, k = j % NKK;
        int rk = (k < MM) ? k : (NN - NKK + k);
        double g = (x == 0 || x == NN-1) ? 1.0 : 2.0;
        FkT[j] = (float)(g * cos(PI * (double)(rk*x) / (double)(NN-1)));
    }
    for (int j = t; j < NKK*NN; j += 256) {
        int k = j / NN, p = j % NN;
        int rk = (k < MM) ? k : (NN - NKK + k);
        double g = (rk == 0 || rk == NN-1) ? 1.0 : 2.0;
        BkT[j] = (float)(g * cos(PI * (double)(rk*p) / (double)(NN-1)));
    }
    for (int j = t; j < MM*NN; j += 256) {
        int l = j / NN, q = j % NN;
        double g = (l == 0) ? 1.0 : 2.0;
        BlT[j] = (float)(g * cos(PI * (double)(q*l) / (double)(NN-1)));
    }
    for (int j = t; j < NLAY*CC*CC; j += 256) {
        int lay = j / (CC*CC), r = j % (CC*CC);
        int i = r / CC, o = r % CC;
        CwT[j] = conv_w[lay*CC*CC + o*CC + i];
    }
}

// ---------------------------------------------------------------------------
// fc0: h[b,c,p,q] = sum_d x[b,p,q,d]*w[d,c] + bias[c].  Block=(b,p), thread=q.
__global__ __launch_bounds__(256) void k_fc0(const float* __restrict__ xin, const float* __restrict__ w,
                                             const float* __restrict__ bias, float* __restrict__ h) {
    __shared__ float xs[NN*3];
    int b = blockIdx.x >> 8, p = blockIdx.x & 255, q = threadIdx.x;
    size_t rowbase = ((size_t)(b*NN + p)*NN) * 3;
    for (int j = q; j < NN*3; j += 256) xs[j] = xin[rowbase + j];
    __syncthreads();
    float v0 = xs[q*3+0], v1 = xs[q*3+1], v2 = xs[q*3+2];
    size_t obase = (size_t)b*CC*PLANE + (size_t)p*NN + q;
    #pragma unroll 8
    for (int c = 0; c < CC; ++c) {
        float hv = bias[c] + v0*w[c] + v1*w[CC+c] + v2*w[2*CC+c];
        h[obase + (size_t)c*PLANE] = hv;
    }
}

// ---------------------------------------------------------------------------
// Forward truncated DCT: per (b,c) plane, G[k,l] = Fk @ h @ FlT.
// Phase 1: FkT via wave-uniform scalar loads; acc[40] in regs (launch_bounds 2 => cap 256 VGPR, no spill).
// Phase 2: P staged in LDS (padded rows), G written to Gt [k][b][c][l].
__global__ __launch_bounds__(256, 2) void k_fwd(const float* __restrict__ h, const float* __restrict__ FkT,
                                                const float* __restrict__ FlT, float* __restrict__ Gt) {
    __shared__ float P[NKK][NN+1];
    int plane = blockIdx.x;                 // b*CC + c
    int t = threadIdx.x;
    const float* hp = h + (size_t)plane * PLANE;
    float acc[NKK];
    #pragma unroll
    for (int k = 0; k < NKK; ++k) acc[k] = 0.f;
    #pragma unroll 2
    for (int x = 0; x < NN; ++x) {
        float hv = hp[x*NN + t];
        const float* fr = &FkT[x*NKK];      // wave-uniform address -> s_load
        #pragma unroll
        for (int k = 0; k < NKK; ++k) acc[k] += fr[k] * hv;
    }
    #pragma unroll
    for (int k = 0; k < NKK; ++k) P[k][t] = acc[k];
    __syncthreads();
    int b = plane >> 6, c = plane & 63;
    for (int j = t; j < NKK*MM; j += 256) {
        int k = j / MM, l = j % MM;
        float a = 0.f;
        for (int y = 0; y < NN; ++y) a += P[k][y] * FlT[y*MM + l];
        Gt[((size_t)(k*BB + b)*CC + c)*MM + l] = a;
    }
}

// ---------------------------------------------------------------------------
// Spectral mode-mix: S[b,o,kb,l] = sum_i G[b,i,kb,l] * w[i,o,kk,l].
__global__ __launch_bounds__(256, 2) void k_spec(const float* __restrict__ Gt, const float* __restrict__ w1,
                                                 const float* __restrict__ w2, float* __restrict__ S) {
    extern __shared__ float gl[];           // BB*CC*MM = 10240 floats ([b][c][l] order)
    int kb = blockIdx.x;
    int t = threadIdx.x;
    const float* chunk = Gt + (size_t)kb * (BB*CC*MM);
    for (int j = t; j < BB*CC*MM; j += 256) gl[j] = chunk[j];
    __syncthreads();
    int o = t & 63, g = t >> 6;
    int b0 = 2*g, b1 = 2*g + 1;
    const float* wp; int kk;
    if (kb < MM) { wp = w1; kk = kb; } else { wp = w2; kk = kb - MM; }
    float a0[MM], a1[MM];
    #pragma unroll
    for (int l = 0; l < MM; ++l) { a0[l] = 0.f; a1[l] = 0.f; }
    for (int i = 0; i < CC; ++i) {
        const float4* wr4 = reinterpret_cast<const float4*>(wp + ((size_t)(i*CC + o)*MM + kk)*MM);
        const float4* g04 = reinterpret_cast<const float4*>(&gl[(b0*CC + i)*MM]);
        const float4* g14 = reinterpret_cast<const float4*>(&gl[(b1*CC + i)*MM]);
        #pragma unroll
        for (int l4 = 0; l4 < MM/4; ++l4) {
            float4 wv = wr4[l4];
            float4 gv0 = g04[l4];
            float4 gv1 = g14[l4];
            a0[4*l4+0] += wv.x*gv0.x; a0[4*l4+1] += wv.y*gv0.y;
            a0[4*l4+2] += wv.z*gv0.z; a0[4*l4+3] += wv.w*gv0.w;
            a1[4*l4+0] += wv.x*gv1.x; a1[4*l4+1] += wv.y*gv1.y;
            a1[4*l4+2] += wv.z*gv1.z; a1[4*l4+3] += wv.w*gv1.w;
        }
    }
    size_t s0 = ((size_t)(b0*CC + o)*NKK + kb)*MM;
    size_t s1 = ((size_t)(b1*CC + o)*NKK + kb)*MM;
    #pragma unroll
    for (int l = 0; l < MM; ++l) { S[s0 + l] = a0[l]; S[s1 + l] = a1[l]; }
}

// ---------------------------------------------------------------------------
// Inverse stage 1: u[pl,p,l] = sum_k BkT[k,p] * S[pl,k,l].  Block = plane (b*CC+o), thread = p.
__global__ __launch_bounds__(256, 2) void k_inv1(const float* __restrict__ S, const float* __restrict__ BkT,
                                                 float* __restrict__ U) {
    __shared__ __align__(16) float sl[NKK*MM];   // 800
    int pl = blockIdx.x, t = threadIdx.x;
    const float* sp = S + (size_t)pl * NKK * MM;
    for (int j = t; j < NKK*MM; j += 256) sl[j] = sp[j];
    __syncthreads();
    float acc[MM];
    #pragma unroll
    for (int l = 0; l < MM; ++l) acc[l] = 0.f;
    for (int k = 0; k < NKK; ++k) {
        float bk = BkT[k*NN + t];
        const float4* s4 = reinterpret_cast<const float4*>(&sl[k*MM]);
        #pragma unroll
        for (int l4 = 0; l4 < MM/4; ++l4) {
            float4 sv = s4[l4];
            acc[4*l4+0] += bk*sv.x; acc[4*l4+1] += bk*sv.y;
            acc[4*l4+2] += bk*sv.z; acc[4*l4+3] += bk*sv.w;
        }
    }
    float* up = U + ((size_t)pl*NN + t)*MM;
    #pragma unroll
    for (int l = 0; l < MM; ++l) up[l] = acc[l];
}

// ---------------------------------------------------------------------------
// Combine IN PLACE (layers with tanh): h[b,o,p,q] = tanh( conv(h)[o]+cb[o]+idct )
// launch_bounds(256,2): VGPR cap 256 so acc[64] lives in registers (no scratch spill).
__global__ __launch_bounds__(256, 2) void k_combine(float* h, const float* __restrict__ U,
                                                    const float* __restrict__ BlT, const float* __restrict__ cwt,
                                                    const float* __restrict__ cb) {
    extern __shared__ float lds[];
    float* cwl = lds;                // CC*CC (layout [i][o])
    float* utl = lds + CC*CC;        // MM*CC (layout [l][o])
    int b = blockIdx.x >> 8, p = blockIdx.x & 255;
    int q = threadIdx.x;
    for (int j = q; j < CC*CC; j += 256) cwl[j] = cwt[j];
    for (int j = q; j < MM*CC; j += 256) {
        int l = j / CC, o = j % CC;
        utl[j] = U[((size_t)(b*CC + o)*NN + p)*MM + l];
    }
    __syncthreads();
    float acc[CC];
    #pragma unroll
    for (int o = 0; o < CC; ++o) acc[o] = cb[o];
    float* hb = h + (size_t)b*CC*PLANE + (size_t)p*NN + q;
    #pragma unroll 4
    for (int i = 0; i < CC; ++i) {
        float hv = hb[(size_t)i*PLANE];
        const float4* cw4 = reinterpret_cast<const float4*>(&cwl[i*CC]);
        #pragma unroll
        for (int o4 = 0; o4 < CC/4; ++o4) {
            float4 wv = cw4[o4];
            acc[4*o4+0] += wv.x*hv; acc[4*o4+1] += wv.y*hv;
            acc[4*o4+2] += wv.z*hv; acc[4*o4+3] += wv.w*hv;
        }
    }
    #pragma unroll 4
    for (int l = 0; l < MM; ++l) {
        float blv = BlT[l*NN + q];
        const float4* u4 = reinterpret_cast<const float4*>(&utl[l*CC]);
        #pragma unroll
        for (int o4 = 0; o4 < CC/4; ++o4) {
            float4 uv = u4[o4];
            acc[4*o4+0] += uv.x*blv; acc[4*o4+1] += uv.y*blv;
            acc[4*o4+2] += uv.z*blv; acc[4*o4+3] += uv.w*blv;
        }
    }
    #pragma unroll
    for (int o = 0; o < CC; ++o) hb[(size_t)o*PLANE] = fast_tanh(acc[o]);
}

// ---------------------------------------------------------------------------
// Last layer fused: combine (no tanh) -> fc1 -> tanh -> fc2, straight to out.
// launch_bounds(256,2): acc[64]+a[16] (~100 VGPR) in registers, no spill.
__global__ __launch_bounds__(256, 2) void k_combine_fc(const float* __restrict__ h, const float* __restrict__ U,
        const float* __restrict__ BlT, const float* __restrict__ cwt, const float* __restrict__ cb,
        const float* __restrict__ w1, const float* __restrict__ b1,
        const float* __restrict__ w2, const float* __restrict__ b2, float* __restrict__ out) {
    extern __shared__ float lds[];
    float* cwl = lds;                // CC*CC (layout [i][o])
    float* utl = lds + CC*CC;        // MM*CC (layout [l][o])
    int b = blockIdx.x >> 8, p = blockIdx.x & 255;
    int q = threadIdx.x;
    for (int j = q; j < CC*CC; j += 256) cwl[j] = cwt[j];
    for (int j = q; j < MM*CC; j += 256) {
        int l = j / CC, o = j % CC;
        utl[j] = U[((size_t)(b*CC + o)*NN + p)*MM + l];
    }
    __syncthreads();
    float acc[CC];
    #pragma unroll
    for (int o = 0; o < CC; ++o) acc[o] = cb[o];
    const float* hb = h + (size_t)b*CC*PLANE + (size_t)p*NN + q;
    #pragma unroll 4
    for (int i = 0; i < CC; ++i) {
        float hv = hb[(size_t)i*PLANE];
        const float4* cw4 = reinterpret_cast<const float4*>(&cwl[i*CC]);
        #pragma unroll
        for (int o4 = 0; o4 < CC/4; ++o4) {
            float4 wv = cw4[o4];
            acc[4*o4+0] += wv.x*hv; acc[4*o4+1] += wv.y*hv;
            acc[4*o4+2] += wv.z*hv; acc[4*o4+3] += wv.w*hv;
        }
    }
    #pragma unroll 4
    for (int l = 0; l < MM; ++l) {
        float blv = BlT[l*NN + q];
        const float4* u4 = reinterpret_cast<const float4*>(&utl[l*CC]);
        #pragma unroll
        for (int o4 = 0; o4 < CC/4; ++o4) {
            float4 uv = u4[o4];
            acc[4*o4+0] += uv.x*blv; acc[4*o4+1] += uv.y*blv;
            acc[4*o4+2] += uv.z*blv; acc[4*o4+3] += uv.w*blv;
        }
    }
    // fc1 -> tanh -> fc2 on the in-register channel vector
    float ov = b2[0];
    const int FCH = 16;
    for (int f0 = 0; f0 < FCD; f0 += FCH) {
        float a[FCH];
        #pragma unroll
        for (int f = 0; f < FCH; ++f) a[f] = b1[f0 + f];
        #pragma unroll 8
        for (int i = 0; i < CC; ++i) {
            float hv = acc[i];
            const float* wr = &w1[i*FCD + f0];   // wave-uniform -> s_load
            #pragma unroll
            for (int f = 0; f < FCH; ++f) a[f] += hv * wr[f];
        }
        #pragma unroll
        for (int f = 0; f < FCH; ++f) ov += fast_tanh(a[f]) * w2[f0 + f];
    }
    out[(size_t)blockIdx.x*NN + q] = ov;
}

// ---------------------------------------------------------------------------
extern "C" void kernel_launch(void* const* d_in, const int* in_sizes, int n_in,
                              void* d_out, int out_size, void* d_ws, size_t ws_size,
                              hipStream_t stream) {
    const float* x      = (const float*)d_in[0];
    const float* fc0_w  = (const float*)d_in[1];
    const float* fc0_b  = (const float*)d_in[2];
    const float* sp_w1  = (const float*)d_in[3];
    const float* sp_w2  = (const float*)d_in[4];
    const float* conv_w = (const float*)d_in[5];
    const float* conv_b = (const float*)d_in[6];
    const float* fc1_w  = (const float*)d_in[7];
    const float* fc1_b  = (const float*)d_in[8];
    const float* fc2_w  = (const float*)d_in[9];
    const float* fc2_b  = (const float*)d_in[10];

    float* ws = (float*)d_ws;
    const size_t HSZ = (size_t)BB*CC*PLANE;           // 33,554,432 floats (134.2 MB)
    float* hA  = ws;
    float* Gt  = hA + HSZ;                            // NKK*BB*CC*MM = 409,600
    float* S   = Gt + (size_t)NKK*BB*CC*MM;           // BB*CC*NKK*MM = 409,600
    float* U   = S  + (size_t)BB*CC*NKK*MM;           // BB*CC*NN*MM  = 2,621,440
    float* FlT = U  + (size_t)BB*CC*NN*MM;            // NN*MM   =  5,120
    float* FkT = FlT + NN*MM;                         // NN*NKK  = 10,240
    float* BkT = FkT + NN*NKK;                        // NKK*NN  = 10,240
    float* BlT = BkT + NKK*NN;                        // MM*NN   =  5,120
    float* CwT = BlT + MM*NN;                         // NLAY*CC*CC = 12,288
    // total = 37,038,080 floats = 148.2 MB of workspace

    k_basis<<<1, 256, 0, stream>>>(FlT, FkT, BkT, BlT, CwT, conv_w);
    k_fc0<<<BB*NN, 256, 0, stream>>>(x, fc0_w, fc0_b, hA);

    for (int lay = 0; lay < NLAY; ++lay) {
        const float* w1 = sp_w1 + (size_t)lay*CC*CC*MM*MM;
        const float* w2 = sp_w2 + (size_t)lay*CC*CC*MM*MM;
        k_fwd<<<BB*CC, 256, 0, stream>>>(hA, FkT, FlT, Gt);
        k_spec<<<NKK, 256, BB*CC*MM*sizeof(float), stream>>>(Gt, w1, w2, S);
        k_inv1<<<BB*CC, 256, 0, stream>>>(S, BkT, U);
        if (lay != NLAY-1) {
            k_combine<<<BB*NN, 256, (CC*CC + MM*CC)*sizeof(float), stream>>>(
                hA, U, BlT, CwT + lay*CC*CC, conv_b + lay*CC);
        } else {
            k_combine_fc<<<BB*NN, 256, (CC*CC + MM*CC)*sizeof(float), stream>>>(
                hA, U, BlT, CwT + lay*CC*CC, conv_b + lay*CC,
                fc1_w, fc1_b, fc2_w, fc2_b, (float*)d_out);
        }
    }
}

// Round 6
// 1216.042 us; speedup vs baseline: 1.3547x; 1.0103x over previous
//
#include <hip/hip_runtime.h>
#include <math.h>

#define BB    8
#define CC    64
#define NN    256
#define MM    20      // retained modes per axis
#define NKK   40      // retained row-modes: {0..19} U {236..255}
#define NLAY  3
#define FCD   128
#define PLANE (NN*NN)

// Fast tanh: clamp + exp-based. v_exp_f32/v_rcp_f32, ~1e-7 abs error, no branches.
__device__ __forceinline__ float fast_tanh(float x) {
    float xc = fminf(fmaxf(x, -15.f), 15.f);
    float e = __expf(2.f * xc);
    return (e - 1.f) / (e + 1.f);
}

// ---------------------------------------------------------------------------
// Basis precompute (double precision on device; tiny).
__global__ __launch_bounds__(256) void k_basis(float* __restrict__ FlT, float* __restrict__ FkT,
                                               float* __restrict__ BkT, float* __restrict__ BlT,
                                               float* __restrict__ CwT, const float* __restrict__ conv_w) {
    int t = threadIdx.x;
    const double PI = 3.14159265358979323846;
    for (int j = t; j < NN*MM; j += 256) {
        int y = j / MM, l = j % MM;
        double g = (y == 0 || y == NN-1) ? 1.0 : 2.0;
        FlT[j] = (float)(g * cos(PI * (double)(l*y) / (double)(NN-1)));
    }
    for (int j = t; j < NN*NKK; j += 256) {
        int x = j / NKK, k = j % NKK;
        int rk = (k < MM) ? k : (NN - NKK + k);
        double g = (x == 0 || x == NN-1) ? 1.0 : 2.0;
        FkT[j] = (float)(g * cos(PI * (double)(rk*x) / (double)(NN-1)));
    }
    for (int j = t; j < NKK*NN; j += 256) {
        int k = j / NN, p = j % NN;
        int rk = (k < MM) ? k : (NN - NKK + k);
        double g = (rk == 0 || rk == NN-1) ? 1.0 : 2.0;
        BkT[j] = (float)(g * cos(PI * (double)(rk*p) / (double)(NN-1)));
    }
    for (int j = t; j < MM*NN; j += 256) {
        int l = j / NN, q = j % NN;
        double g = (l == 0) ? 1.0 : 2.0;
        BlT[j] = (float)(g * cos(PI * (double)(q*l) / (double)(NN-1)));
    }
    for (int j = t; j < NLAY*CC*CC; j += 256) {
        int lay = j / (CC*CC), r = j % (CC*CC);
        int i = r / CC, o = r % CC;
        CwT[j] = conv_w[lay*CC*CC + o*CC + i];
    }
}

// ---------------------------------------------------------------------------
// fc0: h[b,c,p,q] = sum_d x[b,p,q,d]*w[d,c] + bias[c].  Block=(b,p), thread=q.
__global__ __launch_bounds__(256) void k_fc0(const float* __restrict__ xin, const float* __restrict__ w,
                                             const float* __restrict__ bias, float* __restrict__ h) {
    __shared__ float xs[NN*3];
    int b = blockIdx.x >> 8, p = blockIdx.x & 255, q = threadIdx.x;
    size_t rowbase = ((size_t)(b*NN + p)*NN) * 3;
    for (int j = q; j < NN*3; j += 256) xs[j] = xin[rowbase + j];
    __syncthreads();
    float v0 = xs[q*3+0], v1 = xs[q*3+1], v2 = xs[q*3+2];
    size_t obase = (size_t)b*CC*PLANE + (size_t)p*NN + q;
    #pragma unroll 8
    for (int c = 0; c < CC; ++c) {
        float hv = bias[c] + v0*w[c] + v1*w[CC+c] + v2*w[2*CC+c];
        h[obase + (size_t)c*PLANE] = hv;
    }
}

// ---------------------------------------------------------------------------
// Forward truncated DCT: per (b,c) plane, G[k,l] = Fk @ h @ FlT.
// Phase 1: FkT via wave-uniform scalar loads; acc[40] constant-indexed (full unroll) -> VGPRs.
// Phase 2: P staged in LDS (padded rows), G written to Gt [k][b][c][l].
__global__ __launch_bounds__(256, 2) void k_fwd(const float* __restrict__ h, const float* __restrict__ FkT,
                                                const float* __restrict__ FlT, float* __restrict__ Gt) {
    __shared__ float P[NKK][NN+1];
    int plane = blockIdx.x;                 // b*CC + c
    int t = threadIdx.x;
    const float* hp = h + (size_t)plane * PLANE;
    float acc[NKK];
    #pragma unroll
    for (int k = 0; k < NKK; ++k) acc[k] = 0.f;
    #pragma unroll 2
    for (int x = 0; x < NN; ++x) {
        float hv = hp[x*NN + t];
        const float* fr = &FkT[x*NKK];      // wave-uniform address -> s_load
        #pragma unroll
        for (int k = 0; k < NKK; ++k) acc[k] += fr[k] * hv;
    }
    #pragma unroll
    for (int k = 0; k < NKK; ++k) P[k][t] = acc[k];
    __syncthreads();
    int b = plane >> 6, c = plane & 63;
    for (int j = t; j < NKK*MM; j += 256) {
        int k = j / MM, l = j % MM;
        float a = 0.f;
        for (int y = 0; y < NN; ++y) a += P[k][y] * FlT[y*MM + l];
        Gt[((size_t)(k*BB + b)*CC + c)*MM + l] = a;
    }
}

// ---------------------------------------------------------------------------
// Spectral mode-mix: S[b,o,kb,l] = sum_i G[b,i,kb,l] * w[i,o,kk,l].
__global__ __launch_bounds__(256, 2) void k_spec(const float* __restrict__ Gt, const float* __restrict__ w1,
                                                 const float* __restrict__ w2, float* __restrict__ S) {
    extern __shared__ float gl[];           // BB*CC*MM = 10240 floats ([b][c][l] order)
    int kb = blockIdx.x;
    int t = threadIdx.x;
    const float* chunk = Gt + (size_t)kb * (BB*CC*MM);
    for (int j = t; j < BB*CC*MM; j += 256) gl[j] = chunk[j];
    __syncthreads();
    int o = t & 63, g = t >> 6;
    int b0 = 2*g, b1 = 2*g + 1;
    const float* wp; int kk;
    if (kb < MM) { wp = w1; kk = kb; } else { wp = w2; kk = kb - MM; }
    float a0[MM], a1[MM];
    #pragma unroll
    for (int l = 0; l < MM; ++l) { a0[l] = 0.f; a1[l] = 0.f; }
    for (int i = 0; i < CC; ++i) {
        const float4* wr4 = reinterpret_cast<const float4*>(wp + ((size_t)(i*CC + o)*MM + kk)*MM);
        const float4* g04 = reinterpret_cast<const float4*>(&gl[(b0*CC + i)*MM]);
        const float4* g14 = reinterpret_cast<const float4*>(&gl[(b1*CC + i)*MM]);
        #pragma unroll
        for (int l4 = 0; l4 < MM/4; ++l4) {
            float4 wv = wr4[l4];
            float4 gv0 = g04[l4];
            float4 gv1 = g14[l4];
            a0[4*l4+0] += wv.x*gv0.x; a0[4*l4+1] += wv.y*gv0.y;
            a0[4*l4+2] += wv.z*gv0.z; a0[4*l4+3] += wv.w*gv0.w;
            a1[4*l4+0] += wv.x*gv1.x; a1[4*l4+1] += wv.y*gv1.y;
            a1[4*l4+2] += wv.z*gv1.z; a1[4*l4+3] += wv.w*gv1.w;
        }
    }
    size_t s0 = ((size_t)(b0*CC + o)*NKK + kb)*MM;
    size_t s1 = ((size_t)(b1*CC + o)*NKK + kb)*MM;
    #pragma unroll
    for (int l = 0; l < MM; ++l) { S[s0 + l] = a0[l]; S[s1 + l] = a1[l]; }
}

// ---------------------------------------------------------------------------
// Inverse stage 1: u[pl,p,l] = sum_k BkT[k,p] * S[pl,k,l].  Block = plane (b*CC+o), thread = p.
__global__ __launch_bounds__(256, 2) void k_inv1(const float* __restrict__ S, const float* __restrict__ BkT,
                                                 float* __restrict__ U) {
    __shared__ __align__(16) float sl[NKK*MM];   // 800
    int pl = blockIdx.x, t = threadIdx.x;
    const float* sp = S + (size_t)pl * NKK * MM;
    for (int j = t; j < NKK*MM; j += 256) sl[j] = sp[j];
    __syncthreads();
    float acc[MM];
    #pragma unroll
    for (int l = 0; l < MM; ++l) acc[l] = 0.f;
    for (int k = 0; k < NKK; ++k) {
        float bk = BkT[k*NN + t];
        const float4* s4 = reinterpret_cast<const float4*>(&sl[k*MM]);
        #pragma unroll
        for (int l4 = 0; l4 < MM/4; ++l4) {
            float4 sv = s4[l4];
            acc[4*l4+0] += bk*sv.x; acc[4*l4+1] += bk*sv.y;
            acc[4*l4+2] += bk*sv.z; acc[4*l4+3] += bk*sv.w;
        }
    }
    float* up = U + ((size_t)pl*NN + t)*MM;
    #pragma unroll
    for (int l = 0; l < MM; ++l) up[l] = acc[l];
}

// ---------------------------------------------------------------------------
// Combine IN PLACE (layers with tanh): h[b,o,p,q] = tanh( conv(h)[o]+cb[o]+idct )
// acc[] only ever indexed by compile-time constants -> stays in VGPRs.
__global__ __launch_bounds__(256, 2) void k_combine(float* h, const float* __restrict__ U,
                                                    const float* __restrict__ BlT, const float* __restrict__ cwt,
                                                    const float* __restrict__ cb) {
    extern __shared__ float lds[];
    float* cwl = lds;                // CC*CC (layout [i][o])
    float* utl = lds + CC*CC;        // MM*CC (layout [l][o])
    int b = blockIdx.x >> 8, p = blockIdx.x & 255;
    int q = threadIdx.x;
    for (int j = q; j < CC*CC; j += 256) cwl[j] = cwt[j];
    for (int j = q; j < MM*CC; j += 256) {
        int l = j / CC, o = j % CC;
        utl[j] = U[((size_t)(b*CC + o)*NN + p)*MM + l];
    }
    __syncthreads();
    float acc[CC];
    #pragma unroll
    for (int o = 0; o < CC; ++o) acc[o] = cb[o];
    float* hb = h + (size_t)b*CC*PLANE + (size_t)p*NN + q;
    #pragma unroll 4
    for (int i = 0; i < CC; ++i) {
        float hv = hb[(size_t)i*PLANE];
        const float4* cw4 = reinterpret_cast<const float4*>(&cwl[i*CC]);
        #pragma unroll
        for (int o4 = 0; o4 < CC/4; ++o4) {
            float4 wv = cw4[o4];
            acc[4*o4+0] += wv.x*hv; acc[4*o4+1] += wv.y*hv;
            acc[4*o4+2] += wv.z*hv; acc[4*o4+3] += wv.w*hv;
        }
    }
    #pragma unroll 4
    for (int l = 0; l < MM; ++l) {
        float blv = BlT[l*NN + q];
        const float4* u4 = reinterpret_cast<const float4*>(&utl[l*CC]);
        #pragma unroll
        for (int o4 = 0; o4 < CC/4; ++o4) {
            float4 uv = u4[o4];
            acc[4*o4+0] += uv.x*blv; acc[4*o4+1] += uv.y*blv;
            acc[4*o4+2] += uv.z*blv; acc[4*o4+3] += uv.w*blv;
        }
    }
    #pragma unroll
    for (int o = 0; o < CC; ++o) hb[(size_t)o*PLANE] = fast_tanh(acc[o]);
}

// ---------------------------------------------------------------------------
// Last layer fused: combine (no tanh) -> fc1 -> tanh -> fc2, straight to out.
// CRITICAL: the fc1 i-loop is FULLY unrolled so acc[i] is always a
// compile-time-constant index; a partially-unrolled loop (round 4/5) made the
// compiler put acc[64] in scratch -> 345 MB excess FETCH + 377 MB WRITE.
__global__ __launch_bounds__(256, 2) void k_combine_fc(const float* __restrict__ h, const float* __restrict__ U,
        const float* __restrict__ BlT, const float* __restrict__ cwt, const float* __restrict__ cb,
        const float* __restrict__ w1, const float* __restrict__ b1,
        const float* __restrict__ w2, const float* __restrict__ b2, float* __restrict__ out) {
    extern __shared__ float lds[];
    float* cwl = lds;                // CC*CC (layout [i][o])
    float* utl = lds + CC*CC;        // MM*CC (layout [l][o])
    int b = blockIdx.x >> 8, p = blockIdx.x & 255;
    int q = threadIdx.x;
    for (int j = q; j < CC*CC; j += 256) cwl[j] = cwt[j];
    for (int j = q; j < MM*CC; j += 256) {
        int l = j / CC, o = j % CC;
        utl[j] = U[((size_t)(b*CC + o)*NN + p)*MM + l];
    }
    __syncthreads();
    float acc[CC];
    #pragma unroll
    for (int o = 0; o < CC; ++o) acc[o] = cb[o];
    const float* hb = h + (size_t)b*CC*PLANE + (size_t)p*NN + q;
    #pragma unroll 4
    for (int i = 0; i < CC; ++i) {
        float hv = hb[(size_t)i*PLANE];
        const float4* cw4 = reinterpret_cast<const float4*>(&cwl[i*CC]);
        #pragma unroll
        for (int o4 = 0; o4 < CC/4; ++o4) {
            float4 wv = cw4[o4];
            acc[4*o4+0] += wv.x*hv; acc[4*o4+1] += wv.y*hv;
            acc[4*o4+2] += wv.z*hv; acc[4*o4+3] += wv.w*hv;
        }
    }
    #pragma unroll 4
    for (int l = 0; l < MM; ++l) {
        float blv = BlT[l*NN + q];
        const float4* u4 = reinterpret_cast<const float4*>(&utl[l*CC]);
        #pragma unroll
        for (int o4 = 0; o4 < CC/4; ++o4) {
            float4 uv = u4[o4];
            acc[4*o4+0] += uv.x*blv; acc[4*o4+1] += uv.y*blv;
            acc[4*o4+2] += uv.z*blv; acc[4*o4+3] += uv.w*blv;
        }
    }
    // fc1 -> tanh -> fc2 on the in-register channel vector
    float ov = b2[0];
    const int FCH = 16;
    for (int f0 = 0; f0 < FCD; f0 += FCH) {
        float a[FCH];
        #pragma unroll
        for (int f = 0; f < FCH; ++f) a[f] = b1[f0 + f];
        #pragma unroll                      // FULL unroll: acc[i] must be constant-indexed
        for (int i = 0; i < CC; ++i) {
            float hv = acc[i];
            const float* wr = &w1[i*FCD + f0];   // wave-uniform -> s_load
            #pragma unroll
            for (int f = 0; f < FCH; ++f) a[f] += hv * wr[f];
        }
        #pragma unroll
        for (int f = 0; f < FCH; ++f) ov += fast_tanh(a[f]) * w2[f0 + f];
    }
    out[(size_t)blockIdx.x*NN + q] = ov;
}

// ---------------------------------------------------------------------------
extern "C" void kernel_launch(void* const* d_in, const int* in_sizes, int n_in,
                              void* d_out, int out_size, void* d_ws, size_t ws_size,
                              hipStream_t stream) {
    const float* x      = (const float*)d_in[0];
    const float* fc0_w  = (const float*)d_in[1];
    const float* fc0_b  = (const float*)d_in[2];
    const float* sp_w1  = (const float*)d_in[3];
    const float* sp_w2  = (const float*)d_in[4];
    const float* conv_w = (const float*)d_in[5];
    const float* conv_b = (const float*)d_in[6];
    const float* fc1_w  = (const float*)d_in[7];
    const float* fc1_b  = (const float*)d_in[8];
    const float* fc2_w  = (const float*)d_in[9];
    const float* fc2_b  = (const float*)d_in[10];

    float* ws = (float*)d_ws;
    const size_t HSZ = (size_t)BB*CC*PLANE;           // 33,554,432 floats (134.2 MB)
    float* hA  = ws;
    float* Gt  = hA + HSZ;                            // NKK*BB*CC*MM = 409,600
    float* S   = Gt + (size_t)NKK*BB*CC*MM;           // BB*CC*NKK*MM = 409,600
    float* U   = S  + (size_t)BB*CC*NKK*MM;           // BB*CC*NN*MM  = 2,621,440
    float* FlT = U  + (size_t)BB*CC*NN*MM;            // NN*MM   =  5,120
    float* FkT = FlT + NN*MM;                         // NN*NKK  = 10,240
    float* BkT = FkT + NN*NKK;                        // NKK*NN  = 10,240
    float* BlT = BkT + NKK*NN;                        // MM*NN   =  5,120
    float* CwT = BlT + MM*NN;                         // NLAY*CC*CC = 12,288
    // total = 37,038,080 floats = 148.2 MB of workspace

    k_basis<<<1, 256, 0, stream>>>(FlT, FkT, BkT, BlT, CwT, conv_w);
    k_fc0<<<BB*NN, 256, 0, stream>>>(x, fc0_w, fc0_b, hA);

    for (int lay = 0; lay < NLAY; ++lay) {
        const float* w1 = sp_w1 + (size_t)lay*CC*CC*MM*MM;
        const float* w2 = sp_w2 + (size_t)lay*CC*CC*MM*MM;
        k_fwd<<<BB*CC, 256, 0, stream>>>(hA, FkT, FlT, Gt);
        k_spec<<<NKK, 256, BB*CC*MM*sizeof(float), stream>>>(Gt, w1, w2, S);
        k_inv1<<<BB*CC, 256, 0, stream>>>(S, BkT, U);
        if (lay != NLAY-1) {
            k_combine<<<BB*NN, 256, (CC*CC + MM*CC)*sizeof(float), stream>>>(
                hA, U, BlT, CwT + lay*CC*CC, conv_b + lay*CC);
        } else {
            k_combine_fc<<<BB*NN, 256, (CC*CC + MM*CC)*sizeof(float), stream>>>(
                hA, U, BlT, CwT + lay*CC*CC, conv_b + lay*CC,
                fc1_w, fc1_b, fc2_w, fc2_b, (float*)d_out);
        }
    }
}